// Round 10
// baseline (65.176 us; speedup 1.0000x reference)
//
#include <hip/hip_runtime.h>
#include <cfloat>

#define BLOCK 256
#define AU 8         // cloud-A points per thread (registers)
#define KSPLIT 64    // split of the B dimension for grid parallelism
#define RBLOCK 256

typedef float f2 __attribute__((ext_vector_type(2)));
typedef float f8 __attribute__((ext_vector_type(8)));

// Wave-uniform scalar load of one B chunk (2 points, paired-SoA, 32 B).
// SMEM results are NOT scoreboarded: caller must s_waitcnt lgkmcnt(0)
// (+ sched_barrier(0), rule 18) before reading the result.
__device__ __forceinline__ f8 sload8(const float* p) {
    f8 r;
    asm volatile("s_load_dwordx8 %0, %1, 0x0" : "=s"(r) : "s"(p));
    return r;
}
#define LGKM0() do { asm volatile("s_waitcnt lgkmcnt(0)" ::: "memory"); \
                     __builtin_amdgcn_sched_barrier(0); } while (0)

// Rewrite a cloud into paired-SoA chunks: chunk c = points (2c, 2c+1) as
// {x0,x1, y0,y1, z0,z1, h0,h1}, h = 0.5*|b|^2. Odd n: last chunk dups the
// last point (min-safe).
__global__ __launch_bounds__(256) void prep_kernel(
    const float* __restrict__ pc1, int N,
    const float* __restrict__ pc2, int M,
    float* __restrict__ Bp1, float* __restrict__ Bp2)
{
    const int i = blockIdx.x * blockDim.x + threadIdx.x;
    const int C1 = (N + 1) >> 1, C2 = (M + 1) >> 1;
    const float* src; float* dst; int n, c;
    if (i < C1)            { src = pc1; dst = Bp1; n = N; c = i; }
    else if (i < C1 + C2)  { src = pc2; dst = Bp2; n = M; c = i - C1; }
    else return;
    const int j0 = 2 * c, j1 = min(2 * c + 1, n - 1);
    const float x0 = src[3 * j0], y0 = src[3 * j0 + 1], z0 = src[3 * j0 + 2];
    const float x1 = src[3 * j1], y1 = src[3 * j1 + 1], z1 = src[3 * j1 + 2];
    const float h0 = 0.5f * fmaf(x0, x0, fmaf(y0, y0, z0 * z0));
    const float h1 = 0.5f * fmaf(x1, x1, fmaf(y1, y1, z1 * z1));
    float4* d4 = (float4*)(dst + (size_t)c * 8);
    d4[0] = make_float4(x0, x1, y0, y1);
    d4[1] = make_float4(z0, z1, h0, h1);
}

// Both directions in one launch (blockIdx.z). For each a, minimize
// f(b) = 0.5|b|^2 - a.b over the slice; d = 2*f_min + |a|^2.
// B chunks arrive via s_load_dwordx8 into SGPRs (wave-uniform stream,
// scalar pipe) -> NO LDS, NO barriers in the main loop. v_pk_fma_f32
// takes the SGPR pair as one operand. Slices may overlap by one real
// point at odd boundaries (extra mins over real B points are harmless).
__global__ __launch_bounds__(BLOCK, 4) void chamfer_min_kernel(
    const float* __restrict__ pc1, int N,
    const float* __restrict__ pc2, int M,
    const float* __restrict__ Bp1, const float* __restrict__ Bp2,
    float* __restrict__ P1, float* __restrict__ P2)
{
    const int tid = threadIdx.x;

    const float* A; const float* Bp; float* P; int An, Bn;
    if (blockIdx.z == 0) { A = pc1; An = N; Bp = Bp2; Bn = M; P = P1; }
    else                 { A = pc2; An = M; Bp = Bp1; Bn = N; P = P2; }

    const int abase = blockIdx.x * (BLOCK * AU) + tid;
    const int mlen = (((Bn + KSPLIT - 1) / KSPLIT) + 1) & ~1;  // even
    const int m0 = blockIdx.y * mlen;
    const int m1 = min(m0 + mlen, Bn);
    if (m0 >= Bn) return;

    f2 nax2[AU], nay2[AU], naz2[AU];
    #pragma unroll
    for (int u = 0; u < AU; ++u) {
        const int ai = abase + u * BLOCK;
        float x = 0.f, y = 0.f, z = 0.f;
        if (ai < An) {
            x = A[(size_t)ai * 3 + 0];
            y = A[(size_t)ai * 3 + 1];
            z = A[(size_t)ai * 3 + 2];
        }
        nax2[u] = (f2){-x, -x};
        nay2[u] = (f2){-y, -y};
        naz2[u] = (f2){-z, -z};
    }

    float mm[AU];
    #pragma unroll
    for (int u = 0; u < AU; ++u) mm[u] = FLT_MAX;

    const int c0 = m0 >> 1;
    const int c1 = (m1 + 1) >> 1;   // may include 1 pt past slice: still a real B point

    f8 cur = sload8(Bp + (size_t)c0 * 8);
    LGKM0();
    for (int c = c0; c < c1; ++c) {
        const int cn = min(c + 1, c1 - 1);
        f8 nxt = sload8(Bp + (size_t)cn * 8);

        const f2 xx = (f2){cur[0], cur[1]};
        const f2 yy = (f2){cur[2], cur[3]};
        const f2 zz = (f2){cur[4], cur[5]};
        const f2 hv = (f2){cur[6], cur[7]};   // one S->V mov pair, amortized over AU
        #pragma unroll
        for (int u = 0; u < AU; ++u) {
            f2 acc = __builtin_elementwise_fma(naz2[u], zz, hv);
            acc = __builtin_elementwise_fma(nay2[u], yy, acc);
            acc = __builtin_elementwise_fma(nax2[u], xx, acc);
            mm[u] = fminf(fminf(mm[u], acc.x), acc.y);  // v_min3
        }

        LGKM0();     // nxt valid from here
        cur = nxt;
    }

    #pragma unroll
    for (int u = 0; u < AU; ++u) {
        const int ai = abase + u * BLOCK;
        if (ai < An) {
            const float x = nax2[u].x, y = nay2[u].x, z = naz2[u].x;
            const float a2 = fmaf(x, x, fmaf(y, y, z * z));
            float d = fmaf(2.0f, mm[u], a2);
            P[(size_t)blockIdx.y * An + ai] = fmaxf(d, 0.0f);
        }
    }
}

// Stage 1: one thread per point; min across KSPLIT partials, scaled partial mean.
__global__ __launch_bounds__(RBLOCK) void chamfer_reduce1_kernel(
    const float* __restrict__ P1, int N,
    const float* __restrict__ P2, int M,
    double* __restrict__ bsum)
{
    const int tid = threadIdx.x;
    const int g = blockIdx.x * RBLOCK + tid;
    double s = 0.0;
    const int T = N + M;
    if (g < T) {
        const float* base; int stride, i; double scale;
        if (g < N) { base = P1; stride = N; i = g;     scale = 1.0 / (double)N; }
        else       { base = P2; stride = M; i = g - N; scale = 1.0 / (double)M; }
        float v = FLT_MAX;
        #pragma unroll 16
        for (int k = 0; k < KSPLIT; ++k)
            v = fminf(v, base[(size_t)k * stride + i]);
        s = (double)v * scale;
    }
    for (int off = 32; off > 0; off >>= 1)
        s += __shfl_down(s, off, 64);
    __shared__ double wsum[RBLOCK / 64];
    if ((tid & 63) == 0) wsum[tid >> 6] = s;
    __syncthreads();
    if (tid == 0) {
        double tot = 0.0;
        #pragma unroll
        for (int w = 0; w < RBLOCK / 64; ++w) tot += wsum[w];
        bsum[blockIdx.x] = tot;
    }
}

// Stage 2: single block sums the per-block doubles.
__global__ __launch_bounds__(RBLOCK) void chamfer_reduce2_kernel(
    const double* __restrict__ bsum, int nb, float* __restrict__ out)
{
    const int tid = threadIdx.x;
    double s = 0.0;
    for (int i = tid; i < nb; i += RBLOCK) s += bsum[i];
    for (int off = 32; off > 0; off >>= 1)
        s += __shfl_down(s, off, 64);
    __shared__ double wsum[RBLOCK / 64];
    if ((tid & 63) == 0) wsum[tid >> 6] = s;
    __syncthreads();
    if (tid == 0) {
        double tot = 0.0;
        #pragma unroll
        for (int w = 0; w < RBLOCK / 64; ++w) tot += wsum[w];
        out[0] = (float)tot;
    }
}

extern "C" void kernel_launch(void* const* d_in, const int* in_sizes, int n_in,
                              void* d_out, int out_size, void* d_ws, size_t ws_size,
                              hipStream_t stream) {
    const float* pc1 = (const float*)d_in[0];
    const float* pc2 = (const float*)d_in[1];
    const int N = in_sizes[0] / 3;
    const int M = in_sizes[1] / 3;
    const int C1 = (N + 1) >> 1, C2 = (M + 1) >> 1;

    // ws layout (32B-aligned blocks): Bp1, Bp2, P1, P2, bsum
    float* Bp1 = (float*)d_ws;                          // [C1*8]
    float* Bp2 = Bp1 + (size_t)C1 * 8;                  // [C2*8]
    float* P1  = Bp2 + (size_t)C2 * 8;                  // [KSPLIT][N]
    float* P2  = P1 + (size_t)KSPLIT * N;               // [KSPLIT][M]
    double* bsum = (double*)(P2 + (size_t)KSPLIT * M);
    float* out = (float*)d_out;

    const int cTot = C1 + C2;
    prep_kernel<<<(cTot + 255) / 256, 256, 0, stream>>>(pc1, N, pc2, M, Bp1, Bp2);

    const int maxNM = (N > M) ? N : M;
    const int gx = (maxNM + BLOCK * AU - 1) / (BLOCK * AU);
    dim3 grid(gx, KSPLIT, 2);
    chamfer_min_kernel<<<grid, BLOCK, 0, stream>>>(pc1, N, pc2, M, Bp1, Bp2, P1, P2);

    const int gr = (N + M + RBLOCK - 1) / RBLOCK;
    chamfer_reduce1_kernel<<<gr, RBLOCK, 0, stream>>>(P1, N, P2, M, bsum);
    chamfer_reduce2_kernel<<<1, RBLOCK, 0, stream>>>(bsum, gr, out);
}